// Round 5
// baseline (76.328 us; speedup 1.0000x reference)
//
#include <hip/hip_runtime.h>
#include <math.h>

// VectorExpansionCalculator: per-edge radial basis (8 sines w/ cosine cutoff)
// outer-product with real spherical harmonics l=0..3 (n_max = 8,7,6,5).
// Output f32 blocks concat flat: [E,1,8] | [E,3,7] | [E,5,6] | [E,7,5].
// R1: scattered scalar stores -> 137us (store-request bound).
// R2: per-wave LDS staging -> coalesced dwordx4 -> 79us (4.9 TB/s).
// R3/R4: staged block0, native v_sin/v_cos, nontemporal stores -> 74.9us.
// R5 (this): bijective XCD-chunked block swizzle (contiguous output span per
//            XCD L2 -> long HBM write bursts) + conflict-free blocked layout
//            for block0 staging (was 16-way bank conflict on ds_write).

#define RCUT 5.0f
#define EPSF 1e-12f

typedef float fx4 __attribute__((ext_vector_type(4)));

// Stage S floats/lane into wave-private LDS (linear [64][S]), then flush the
// wave's contiguous 64*S-float region with coalesced nontemporal 16B stores.
template <int S>
__device__ __forceinline__ void stage_flush(float* __restrict__ lw,
                                            const float* __restrict__ vals,
                                            int lane,
                                            fx4* __restrict__ g4) {
#pragma unroll
  for (int i = 0; i < S; ++i) lw[lane * S + i] = vals[i];
  // LDS is in-order per wave; compiler inserts lgkmcnt before dependent reads.
  const fx4* l4 = reinterpret_cast<const fx4*>(lw);
  constexpr int NF4 = 16 * S;                 // 64*S/4 16B-vectors
  constexpr int NITER = (NF4 + 63) / 64;
#pragma unroll
  for (int it = 0; it < NITER; ++it) {
    int k = lane + it * 64;
    if ((NF4 % 64 == 0) || k < NF4) __builtin_nontemporal_store(l4[k], &g4[k]);
  }
}

__global__ __launch_bounds__(256) void vexp_kernel(const float* __restrict__ v,
                                                   float* __restrict__ out, int E,
                                                   int nwg) {
  __shared__ fx4 lbuf[4][560];  // per-wave staging: 35*64 floats = 8960 B
  const int lane = threadIdx.x & 63;
  const int wave = threadIdx.x >> 6;

  // Bijective XCD-chunked swizzle (8 XCDs, default assignment is bid%8):
  // XCD x gets a contiguous chunk of work ids -> contiguous output span per
  // XCD L2 -> long address-local HBM write bursts instead of 8-way dribble.
  int x = blockIdx.x & 7;
  int i = blockIdx.x >> 3;
  int q = nwg >> 3, r = nwg & 7;
  int wg = (x < r) ? (x * (q + 1) + i) : (r * (q + 1) + (x - r) * q + i);

  const long long e0 = ((long long)wg * 4 + wave) * 64;
  if (e0 >= E) return;
  const bool fullwave = (e0 + 64 <= (long long)E);
  const int e = (int)e0 + lane;
  const bool valid = e < E;

  float xc = 0.0f, yc = 0.0f, zc = 0.0f;
  if (valid) {
    xc = v[3 * (size_t)e + 0];
    yc = v[3 * (size_t)e + 1];
    zc = v[3 * (size_t)e + 2];
  }

  float r2 = xc * xc + yc * yc + zc * zc;
  float rr = sqrtf(r2);
  float ir = 1.0f / (rr + EPSF);

  // ---- radial basis: rb[n] = fcut * sin((n+1)*pi*r/RCUT) / (r+eps) ----
  float theta = (3.14159265358979323846f / RCUT) * rr;
  float s = __sinf(theta);
  float c = __cosf(theta);
  float fcut = (rr < RCUT) ? 0.5f * (c + 1.0f) : 0.0f;
  float g = fcut * ir;

  float rb[8];
  {
    float twoc = 2.0f * c;
    float sp = 0.0f, sn = s;
    rb[0] = sn * g;
#pragma unroll
    for (int n = 1; n < 8; ++n) {
      float s2 = twoc * sn - sp;
      sp = sn;
      sn = s2;
      rb[n] = sn * g;
    }
  }

  // ---- unit direction + spherical harmonics ----
  float ux = xc * ir, uy = yc * ir, uz = zc * ir;
  float xx = ux * ux, yy = uy * uy, zz = uz * uz;

  const float c1 = 0.48860251190291992f;
  float sh1[3] = {c1 * uy, c1 * uz, c1 * ux};

  const float c2a = 1.09254843059207907f;
  const float c2b = 0.31539156525252001f;
  const float c2c = 0.54627421529603953f;
  float sh2[5] = {c2a * ux * uy, c2a * uy * uz, c2b * (2.0f * zz - xx - yy),
                  c2a * ux * uz, c2c * (xx - yy)};

  const float c3a = 0.59004358992664352f;
  const float c3b = 2.89061144264055405f;
  const float c3c = 0.45704579946446574f;
  const float c3d = 0.37317633259011546f;
  const float c3e = 1.44530572132027702f;
  float sh3[7] = {c3a * uy * (3.0f * xx - yy),
                  c3b * ux * uy * uz,
                  c3c * uy * (4.0f * zz - xx - yy),
                  c3d * uz * (2.0f * zz - 3.0f * xx - 3.0f * yy),
                  c3c * ux * (4.0f * zz - xx - yy),
                  c3e * uz * (xx - yy),
                  c3a * ux * (xx - 3.0f * yy)};

  const size_t E_ = (size_t)E;
  float* lw = reinterpret_cast<float*>(lbuf[wave]);
  fx4* l4 = lbuf[wave];
  float vals[35];

  // ---- block 0: [E,1,8] @ 0 — blocked [chunk][lane] fx4 layout in LDS ----
  // ds_write: lanes adjacent 16B -> conflict-free (vs 16-way at stride 32B).
  const float y0c = 0.28209479177387814f;
  if (fullwave) {
    fx4 a0 = {y0c * rb[0], y0c * rb[1], y0c * rb[2], y0c * rb[3]};
    fx4 b0 = {y0c * rb[4], y0c * rb[5], y0c * rb[6], y0c * rb[7]};
    l4[lane] = a0;
    l4[64 + lane] = b0;
    fx4* g4 = reinterpret_cast<fx4*>(out + (size_t)e0 * 8);
#pragma unroll
    for (int it = 0; it < 2; ++it) {
      int k = lane + it * 64;
      int slot = ((k & 1) << 6) + (k >> 1);  // out chunk k = edge k>>1, half k&1
      __builtin_nontemporal_store(l4[slot], &g4[k]);
    }
  } else if (valid) {
    float* o = out + (size_t)e * 8;
#pragma unroll
    for (int n = 0; n < 8; ++n) o[n] = y0c * rb[n];
  }

  // ---- block 1: [E,3,7] @ 8E ----
#pragma unroll
  for (int m = 0; m < 3; ++m)
#pragma unroll
    for (int n = 0; n < 7; ++n) vals[m * 7 + n] = sh1[m] * rb[n];
  if (fullwave) {
    stage_flush<21>(lw, vals, lane,
                    reinterpret_cast<fx4*>(out + 8 * E_ + (size_t)e0 * 21));
  } else if (valid) {
    float* o = out + 8 * E_ + (size_t)e * 21;
#pragma unroll
    for (int i2 = 0; i2 < 21; ++i2) o[i2] = vals[i2];
  }

  // ---- block 2: [E,5,6] @ 29E ----
#pragma unroll
  for (int m = 0; m < 5; ++m)
#pragma unroll
    for (int n = 0; n < 6; ++n) vals[m * 6 + n] = sh2[m] * rb[n];
  if (fullwave) {
    stage_flush<30>(lw, vals, lane,
                    reinterpret_cast<fx4*>(out + 29 * E_ + (size_t)e0 * 30));
  } else if (valid) {
    float* o = out + 29 * E_ + (size_t)e * 30;
#pragma unroll
    for (int i2 = 0; i2 < 30; ++i2) o[i2] = vals[i2];
  }

  // ---- block 3: [E,7,5] @ 59E ----
#pragma unroll
  for (int m = 0; m < 7; ++m)
#pragma unroll
    for (int n = 0; n < 5; ++n) vals[m * 5 + n] = sh3[m] * rb[n];
  if (fullwave) {
    stage_flush<35>(lw, vals, lane,
                    reinterpret_cast<fx4*>(out + 59 * E_ + (size_t)e0 * 35));
  } else if (valid) {
    float* o = out + 59 * E_ + (size_t)e * 35;
#pragma unroll
    for (int i2 = 0; i2 < 35; ++i2) o[i2] = vals[i2];
  }
}

extern "C" void kernel_launch(void* const* d_in, const int* in_sizes, int n_in,
                              void* d_out, int out_size, void* d_ws, size_t ws_size,
                              hipStream_t stream) {
  const float* v = (const float*)d_in[0];
  float* out = (float*)d_out;
  int E = in_sizes[0] / 3;
  int waves = (E + 63) / 64;
  int grid = (waves + 3) / 4;  // 4 waves (256 threads) per block
  vexp_kernel<<<grid, 256, 0, stream>>>(v, out, E, grid);
}